// Round 10
// baseline (300.048 us; speedup 1.0000x reference)
//
#include <hip/hip_runtime.h>
#include <hip/hip_bf16.h>
#include <cstdint>
#include <cstddef>

#define KDIM 4096   // out features
#define NDIM 4096   // in features (contraction dim)
#define NGRP 32
#define GSZ  128
#define MDIM 8192   // 4 * 2048 rows of x
#define NT   (NDIM / 64)   // 64 K-tiles of BK=64

typedef unsigned short ushort_t;
typedef float f32x4 __attribute__((ext_vector_type(4)));
typedef __bf16 bf16x8 __attribute__((ext_vector_type(8)));
typedef unsigned short u16x8 __attribute__((ext_vector_type(8)));
typedef int i32x4 __attribute__((ext_vector_type(4)));

// RTNE float -> bf16
__device__ __forceinline__ ushort_t f2bf(float f) {
    union { float f; unsigned u; } v; v.f = f;
    unsigned r = v.u + 0x7FFFu + ((v.u >> 16) & 1u);
    return (ushort_t)(r >> 16);
}

__device__ __forceinline__ void gload_lds16(const void* g, void* l) {
    __builtin_amdgcn_global_load_lds(
        (const __attribute__((address_space(1))) unsigned int*)g,
        (__attribute__((address_space(3))) unsigned int*)l,
        16, 0, 0);
}

// ---------------- Pass 1a: dequantize W -> bf16 [K, N] ----------------
__global__ __launch_bounds__(256) void dq_w_kernel(
    const int* __restrict__ Wq, const float* __restrict__ scales,
    const float* __restrict__ zeros, const int* __restrict__ mask,
    const float* __restrict__ scale2, ushort_t* __restrict__ Wb) {
    int gid = blockIdx.x * 256 + threadIdx.x;
    int e0 = gid * 8;
    int k = e0 >> 12;
    int n = e0 & (NDIM - 1);
    int g = n >> 7;
    float ss = scales[k * NGRP + g] * scale2[k];
    float z  = zeros[k * NGRP + g];
    i32x4 q0 = *(const i32x4*)(Wq + e0);
    i32x4 q1 = *(const i32x4*)(Wq + e0 + 4);
    i32x4 m0 = *(const i32x4*)(mask + e0);
    i32x4 m1 = *(const i32x4*)(mask + e0 + 4);
    u16x8 r;
#pragma unroll
    for (int i = 0; i < 4; ++i) r[i]     = f2bf(((float)q0[i] - z) * ss * (float)m0[i]);
#pragma unroll
    for (int i = 0; i < 4; ++i) r[4 + i] = f2bf(((float)q1[i] - z) * ss * (float)m1[i]);
    *(u16x8*)(Wb + e0) = r;
}

// ---------------- Pass 1b: convert x fp32 -> bf16 [M, N] ----------------
__global__ __launch_bounds__(256) void cvt_x_kernel(
    const float* __restrict__ x, ushort_t* __restrict__ Xb) {
    int gid = blockIdx.x * 256 + threadIdx.x;
    size_t e0 = (size_t)gid * 8;
    f32x4 a = *(const f32x4*)(x + e0);
    f32x4 b = *(const f32x4*)(x + e0 + 4);
    u16x8 r;
#pragma unroll
    for (int i = 0; i < 4; ++i) r[i] = f2bf(a[i]);
#pragma unroll
    for (int i = 0; i < 4; ++i) r[4 + i] = f2bf(b[i]);
    *(u16x8*)(Xb + e0) = r;
}

// ---------------- Pass 2: 256x256-tile bf16 GEMM, persistent 2-half ------
// out[m][k] = sum_n Xb[m][n] * Wb[k][n] + bias[k]
// Hot loop = round-6-proven kernel EXACTLY (4-barrier TILE2, read
// pipelining, vmcnt(6) ledger, XOR swizzle, 16x16x32 MFMA, 24 b128/tile).
// NEW: persistent blocks — grid 256, each block computes (mtile0, ntile)
// then (mtile0+16, ntile). The half-2 prologue DMAs are issued BEFORE the
// half-1 epilogue (store burst hides DMA latency; loop-top vmcnt(6) then
// counts stores as newest outstanding ops, so it conservatively forces all
// 14 prologue loads — correct). Same ntile both halves -> W-panel DMAs of
// half 2 hit L2. BAR after tile 63 (all live reads retired via their
// consumer clusters) before restaging; trailing dead pre-reads may sample
// overwritten LDS into dead regs — harmless.

#define LDS_SLOT 65536
#define LDS_A0   0
#define LDS_A1   16384
#define LDS_B0   32768
#define LDS_B1   49152

#define STAGE(ldsHalf, gbase) do { \
    gload_lds16((gbase) + goff0, (ldsHalf) + ldsoff0); \
    gload_lds16((gbase) + goff1, (ldsHalf) + ldsoff1); } while (0)

#define READ_A(S, QM) do { \
    const char* Ab_ = lds + (S)*LDS_SLOT + (QM)*16384 + rowA; \
    a00 = *(const bf16x8*)(Ab_ + 0*2048 + cb0); \
    a10 = *(const bf16x8*)(Ab_ + 1*2048 + cb0); \
    a20 = *(const bf16x8*)(Ab_ + 2*2048 + cb0); \
    a30 = *(const bf16x8*)(Ab_ + 3*2048 + cb0); \
    a01 = *(const bf16x8*)(Ab_ + 0*2048 + cb1); \
    a11 = *(const bf16x8*)(Ab_ + 1*2048 + cb1); \
    a21 = *(const bf16x8*)(Ab_ + 2*2048 + cb1); \
    a31 = *(const bf16x8*)(Ab_ + 3*2048 + cb1); \
} while (0)

#define READ_B(S, QN, B00, B10, B01, B11) do { \
    const char* Bb_ = lds + (S)*LDS_SLOT + 32768 + (QN)*16384 + rowB; \
    B00 = *(const bf16x8*)(Bb_ + 0*2048 + cb0); \
    B10 = *(const bf16x8*)(Bb_ + 1*2048 + cb0); \
    B01 = *(const bf16x8*)(Bb_ + 0*2048 + cb1); \
    B11 = *(const bf16x8*)(Bb_ + 1*2048 + cb1); \
} while (0)

#define MFMA16(QM, QN, B00, B10, B01, B11) do { \
    acc[(QM)*4+0][(QN)*2+0] = __builtin_amdgcn_mfma_f32_16x16x32_bf16(a00, B00, acc[(QM)*4+0][(QN)*2+0], 0,0,0); \
    acc[(QM)*4+1][(QN)*2+0] = __builtin_amdgcn_mfma_f32_16x16x32_bf16(a10, B00, acc[(QM)*4+1][(QN)*2+0], 0,0,0); \
    acc[(QM)*4+2][(QN)*2+0] = __builtin_amdgcn_mfma_f32_16x16x32_bf16(a20, B00, acc[(QM)*4+2][(QN)*2+0], 0,0,0); \
    acc[(QM)*4+3][(QN)*2+0] = __builtin_amdgcn_mfma_f32_16x16x32_bf16(a30, B00, acc[(QM)*4+3][(QN)*2+0], 0,0,0); \
    acc[(QM)*4+0][(QN)*2+1] = __builtin_amdgcn_mfma_f32_16x16x32_bf16(a00, B10, acc[(QM)*4+0][(QN)*2+1], 0,0,0); \
    acc[(QM)*4+1][(QN)*2+1] = __builtin_amdgcn_mfma_f32_16x16x32_bf16(a10, B10, acc[(QM)*4+1][(QN)*2+1], 0,0,0); \
    acc[(QM)*4+2][(QN)*2+1] = __builtin_amdgcn_mfma_f32_16x16x32_bf16(a20, B10, acc[(QM)*4+2][(QN)*2+1], 0,0,0); \
    acc[(QM)*4+3][(QN)*2+1] = __builtin_amdgcn_mfma_f32_16x16x32_bf16(a30, B10, acc[(QM)*4+3][(QN)*2+1], 0,0,0); \
    acc[(QM)*4+0][(QN)*2+0] = __builtin_amdgcn_mfma_f32_16x16x32_bf16(a01, B01, acc[(QM)*4+0][(QN)*2+0], 0,0,0); \
    acc[(QM)*4+1][(QN)*2+0] = __builtin_amdgcn_mfma_f32_16x16x32_bf16(a11, B01, acc[(QM)*4+1][(QN)*2+0], 0,0,0); \
    acc[(QM)*4+2][(QN)*2+0] = __builtin_amdgcn_mfma_f32_16x16x32_bf16(a21, B01, acc[(QM)*4+2][(QN)*2+0], 0,0,0); \
    acc[(QM)*4+3][(QN)*2+0] = __builtin_amdgcn_mfma_f32_16x16x32_bf16(a31, B01, acc[(QM)*4+3][(QN)*2+0], 0,0,0); \
    acc[(QM)*4+0][(QN)*2+1] = __builtin_amdgcn_mfma_f32_16x16x32_bf16(a01, B11, acc[(QM)*4+0][(QN)*2+1], 0,0,0); \
    acc[(QM)*4+1][(QN)*2+1] = __builtin_amdgcn_mfma_f32_16x16x32_bf16(a11, B11, acc[(QM)*4+1][(QN)*2+1], 0,0,0); \
    acc[(QM)*4+2][(QN)*2+1] = __builtin_amdgcn_mfma_f32_16x16x32_bf16(a21, B11, acc[(QM)*4+2][(QN)*2+1], 0,0,0); \
    acc[(QM)*4+3][(QN)*2+1] = __builtin_amdgcn_mfma_f32_16x16x32_bf16(a31, B11, acc[(QM)*4+3][(QN)*2+1], 0,0,0); \
} while (0)

#define BAR    asm volatile("s_barrier" ::: "memory")
#define VMCNT6 asm volatile("s_waitcnt vmcnt(6)" ::: "memory")
#define VMCNT0 asm volatile("s_waitcnt vmcnt(0)" ::: "memory")
#define SB     __builtin_amdgcn_sched_barrier(0)

#define CLUSTER(QM, QN, B00, B10, B01, B11) do { \
    SB; __builtin_amdgcn_s_setprio(1); \
    MFMA16(QM, QN, B00, B10, B01, B11); \
    __builtin_amdgcn_s_setprio(0); SB; \
} while (0)

// One K-tile (round-6-proven). Entry: a=A0[t], P=B0[t]. Exit: a=A0[t+1],
// Q=B0[t+1] (P/Q roles swap per tile).
#define TILE2(S, P00,P10,P01,P11, Q00,Q10,Q01,Q11, ST0, ST1, ST2, ST3, BND) do { \
    ST0; \
    CLUSTER(0, 0, P00,P10,P01,P11); \
    READ_B(S, 1, Q00,Q10,Q01,Q11); \
    BAR; \
    ST1; \
    CLUSTER(0, 1, Q00,Q10,Q01,Q11); \
    READ_A(S, 1); \
    BAR; \
    ST2; \
    CLUSTER(1, 1, Q00,Q10,Q01,Q11); \
    BAR; \
    ST3; \
    BND; \
    BAR; \
    READ_B((S)^1, 0, Q00,Q10,Q01,Q11); \
    CLUSTER(1, 0, P00,P10,P01,P11); \
    READ_A((S)^1, 0); \
} while (0)

// Prologue stage set for one M-half-pair (14 loads; leaves B0[1],B1[1],A1[1]
// as the 6 newest loads -> loop-top VMCNT6 forces tile 0's four halves).
#define PROLOGUE_STAGES(XR0, XR1) do { \
    STAGE(lds + 0*LDS_SLOT + LDS_A0, (XR0) + 0); \
    STAGE(lds + 0*LDS_SLOT + LDS_B0, Wrow0 + 0); \
    STAGE(lds + 0*LDS_SLOT + LDS_B1, Wrow1 + 0); \
    STAGE(lds + 0*LDS_SLOT + LDS_A1, (XR1) + 0); \
    STAGE(lds + 1*LDS_SLOT + LDS_B0, Wrow0 + 64); \
    STAGE(lds + 1*LDS_SLOT + LDS_B1, Wrow1 + 64); \
    STAGE(lds + 1*LDS_SLOT + LDS_A1, (XR1) + 64); \
} while (0)

__global__ __launch_bounds__(512, 2) void gemm8p_kernel(
    const ushort_t* __restrict__ Xb, const ushort_t* __restrict__ Wb,
    const float* __restrict__ bias, float* __restrict__ out) {
    extern __shared__ char lds[];

    const int tid   = threadIdx.x;
    const int lane  = tid & 63;
    const int wid   = tid >> 6;      // 0..7
    const int wm    = wid >> 2;      // 0..1  (M sub-block within each half)
    const int wn    = wid & 3;       // 0..3  (N sub-block within each half)
    const int fr    = lane & 15;
    const int khalf = lane >> 4;     // 0..3

    // T1: bijective XCD swizzle (256 % 8 == 0, chunk = 32)
    const int orig  = blockIdx.x;
    const int wgid  = ((orig & 7) << 5) | (orig >> 3);
    const int ntile  = wgid & 15;    // 16 N-tiles
    const int mtile0 = wgid >> 4;    // 0..15 (handles mtile0 and mtile0+16)
    const int n0 = ntile << 8;

    // stage addressing: granule g = l*512 + tid; LDS linear; global pre-swizzled
    const int g0 = tid, g1 = 512 + tid;
    const size_t goff0 = (size_t)(g0 >> 3) * NDIM + (size_t)((((g0 & 7) ^ ((g0 >> 3) & 7))) << 3);
    const size_t goff1 = (size_t)(g1 >> 3) * NDIM + (size_t)((((g1 & 7) ^ ((g1 >> 3) & 7))) << 3);
    const int ldsoff0 = (wid << 10);          // wave-uniform base, load 0
    const int ldsoff1 = 8192 + (wid << 10);   // load 1

    // fragment read offsets (bytes within a [128][64] bf16 half-buffer)
    const int rowA = ((wm << 6) + fr) << 7;               // (wm*64+fr)*128
    const int rowB = ((wn << 5) + fr) << 7;               // (wn*32+fr)*128
    const int cb0  = ((khalf)     ^ (fr & 7)) << 4;       // kk=0 chunk (swizzled)
    const int cb1  = ((4 + khalf) ^ (fr & 7)) << 4;       // kk=1 chunk

    const ushort_t* Wrow0 = Wb + (size_t)n0 * NDIM;
    const ushort_t* Wrow1 = Wb + (size_t)(n0 + 128) * NDIM;

    // bias fragment (same columns for both halves)
    float bv[4];
#pragma unroll
    for (int j = 0; j < 4; ++j)
        bv[j] = bias[n0 + ((j >> 1) << 7) + (wn << 5) + ((j & 1) << 4) + fr];

    // fragment registers: a = current A-half; p/q = B0/B1 (roles alternate)
    bf16x8 a00, a10, a20, a30, a01, a11, a21, a31;
    bf16x8 p00, p10, p01, p11, q00, q10, q01, q11;
    f32x4 acc[8][4];

    const ushort_t* Xrow0;
    const ushort_t* Xrow1;

    // Initial prologue (half 0)
    Xrow0 = Xb + (size_t)(mtile0 << 8) * NDIM;
    Xrow1 = Xrow0 + (size_t)128 * NDIM;
    PROLOGUE_STAGES(Xrow0, Xrow1);

#pragma unroll 1
    for (int half = 0; half < 2; ++half) {
        const int m0 = (mtile0 + (half << 4)) << 8;
        Xrow0 = Xb + (size_t)m0 * NDIM;
        Xrow1 = Xrow0 + (size_t)128 * NDIM;
#pragma unroll
        for (int i = 0; i < 8; ++i)
#pragma unroll
            for (int j = 0; j < 4; ++j) { f32x4 z = {0.f,0.f,0.f,0.f}; acc[i][j] = z; }

        // Loop entry: vmcnt(6) forces tile 0's four halves (for half 1 the
        // 6 newest outstanding ops are epilogue stores -> over-forces, safe).
        VMCNT6;
        BAR;
        READ_A(0, 0);
        READ_B(0, 0, p00, p10, p01, p11);

        // Hot loop: tiles 0..61 (round-6 ledger).
#pragma unroll 1
        for (int kt2 = 0; kt2 < NT / 2 - 1; ++kt2) {
            const int te = 2 * kt2, to = te + 1;
            TILE2(0, p00,p10,p01,p11, q00,q10,q01,q11,
                  STAGE(lds + 1*LDS_SLOT + LDS_A0, Xrow0 + (te + 1) * 64),
                  STAGE(lds + 0*LDS_SLOT + LDS_B0, Wrow0 + (te + 2) * 64),
                  STAGE(lds + 0*LDS_SLOT + LDS_B1, Wrow1 + (te + 2) * 64),
                  STAGE(lds + 0*LDS_SLOT + LDS_A1, Xrow1 + (te + 2) * 64),
                  VMCNT6);
            TILE2(1, q00,q10,q01,q11, p00,p10,p01,p11,
                  STAGE(lds + 0*LDS_SLOT + LDS_A0, Xrow0 + (to + 1) * 64),
                  STAGE(lds + 1*LDS_SLOT + LDS_B0, Wrow0 + (to + 2) * 64),
                  STAGE(lds + 1*LDS_SLOT + LDS_B1, Wrow1 + (to + 2) * 64),
                  STAGE(lds + 1*LDS_SLOT + LDS_A1, Xrow1 + (to + 2) * 64),
                  VMCNT6);
        }
        // Peeled tile 62 (slot 0): only A0[63] stage; vmcnt(0) at boundary.
        TILE2(0, p00,p10,p01,p11, q00,q10,q01,q11,
              STAGE(lds + 1*LDS_SLOT + LDS_A0, Xrow0 + 63 * 64),
              (void)0, (void)0, (void)0,
              VMCNT0);
        // Peeled tile 63 (slot 1): no stages; trailing pre-reads dead.
        TILE2(1, q00,q10,q01,q11, p00,p10,p01,p11,
              (void)0, (void)0, (void)0, (void)0, (void)0);

        // All waves' live LDS reads are retired (consumed by clusters).
        BAR;

        // Pre-epilogue prologue for half 1: DMA latency hides under the
        // store burst below.
        if (half == 0) {
            const ushort_t* Xn0 = Xb + (size_t)((mtile0 + 16) << 8) * NDIM;
            const ushort_t* Xn1 = Xn0 + (size_t)128 * NDIM;
            PROLOGUE_STAGES(Xn0, Xn1);
        }

        // Epilogue: C/D layout col=lane&15, row=(lane>>4)*4+reg.
#pragma unroll
        for (int i = 0; i < 8; ++i) {
            const int row = m0 + ((i >> 2) << 7) + (wm << 6) + ((i & 3) << 4) + (khalf << 2);
#pragma unroll
            for (int j = 0; j < 4; ++j) {
                const int col = n0 + ((j >> 1) << 7) + (wn << 5) + ((j & 1) << 4) + fr;
#pragma unroll
                for (int q = 0; q < 4; ++q)
                    out[(size_t)(row + q) * KDIM + col] = acc[i][j][q] + bv[j];
            }
        }
    }
}

// ---------------- Fallback (only if ws too small): naive fused ----------------
__global__ __launch_bounds__(256) void naive_kernel(
    const float* __restrict__ x, const int* __restrict__ Wq,
    const float* __restrict__ scales, const float* __restrict__ zeros,
    const int* __restrict__ mask, const float* __restrict__ scale2,
    const float* __restrict__ bias, float* __restrict__ out) {
    size_t o = (size_t)blockIdx.x * 256 + threadIdx.x;
    int m = (int)(o >> 12);
    int k = (int)(o & (KDIM - 1));
    const float* xr = x + (size_t)m * NDIM;
    const int* wr = Wq + (size_t)k * NDIM;
    const int* mr = mask + (size_t)k * NDIM;
    float s2 = scale2[k];
    float acc = 0.f;
    for (int g = 0; g < NGRP; ++g) {
        float ss = scales[k * NGRP + g] * s2;
        float z = zeros[k * NGRP + g];
        for (int n = g * GSZ; n < (g + 1) * GSZ; ++n)
            acc += xr[n] * (((float)wr[n] - z) * ss * (float)mr[n]);
    }
    out[o] = acc + bias[k];
}

extern "C" void kernel_launch(void* const* d_in, const int* in_sizes, int n_in,
                              void* d_out, int out_size, void* d_ws, size_t ws_size,
                              hipStream_t stream) {
    const float* x      = (const float*)d_in[0];
    const int*   Wq     = (const int*)d_in[1];
    const float* scales = (const float*)d_in[2];
    const float* zeros  = (const float*)d_in[3];
    const int*   mask   = (const int*)d_in[4];
    const float* scale2 = (const float*)d_in[5];
    const float* bias   = (const float*)d_in[6];
    float* out = (float*)d_out;

    const size_t needW = (size_t)KDIM * NDIM * sizeof(ushort_t);  // 32 MiB
    const size_t needX = (size_t)MDIM * NDIM * sizeof(ushort_t);  // 64 MiB

    if (ws_size >= needW + needX) {
        ushort_t* Wb = (ushort_t*)d_ws;
        ushort_t* Xb = (ushort_t*)((char*)d_ws + needW);
        hipLaunchKernelGGL(dq_w_kernel, dim3((KDIM * NDIM / 8) / 256), dim3(256),
                           0, stream, Wq, scales, zeros, mask, scale2, Wb);
        hipLaunchKernelGGL(cvt_x_kernel, dim3((MDIM * NDIM / 8) / 256), dim3(256),
                           0, stream, x, Xb);
        hipFuncSetAttribute((const void*)gemm8p_kernel,
                            hipFuncAttributeMaxDynamicSharedMemorySize, 131072);
        // persistent: 256 blocks, each does (mtile0, ntile) and (mtile0+16, ntile)
        hipLaunchKernelGGL(gemm8p_kernel, dim3((MDIM / 256 / 2) * (KDIM / 256)), dim3(512),
                           131072, stream, Xb, Wb, bias, out);
    } else {
        hipLaunchKernelGGL(naive_kernel, dim3((MDIM * KDIM) / 256), dim3(256),
                           0, stream, x, Wq, scales, zeros, mask, scale2, bias, out);
    }
}

// Round 11
// 270.684 us; speedup vs baseline: 1.1085x; 1.1085x over previous
//
#include <hip/hip_runtime.h>
#include <hip/hip_bf16.h>
#include <cstdint>
#include <cstddef>

#define KDIM 4096   // out features
#define NDIM 4096   // in features (contraction dim)
#define NGRP 32
#define GSZ  128
#define MDIM 8192   // 4 * 2048 rows of x
#define NT   (NDIM / 64)   // 64 K-tiles of BK=64

typedef unsigned short ushort_t;
typedef float f32x4 __attribute__((ext_vector_type(4)));
typedef __bf16 bf16x8 __attribute__((ext_vector_type(8)));
typedef unsigned short u16x8 __attribute__((ext_vector_type(8)));
typedef int i32x4 __attribute__((ext_vector_type(4)));

// RTNE float -> bf16
__device__ __forceinline__ ushort_t f2bf(float f) {
    union { float f; unsigned u; } v; v.f = f;
    unsigned r = v.u + 0x7FFFu + ((v.u >> 16) & 1u);
    return (ushort_t)(r >> 16);
}

__device__ __forceinline__ void gload_lds16(const void* g, void* l) {
    __builtin_amdgcn_global_load_lds(
        (const __attribute__((address_space(1))) unsigned int*)g,
        (__attribute__((address_space(3))) unsigned int*)l,
        16, 0, 0);
}

// ------- Pass 1 (fused): dequantize W -> bf16 [K,N]  +  convert x -> bf16 --
// blocks [0, NBLK_W): dq_w   ; blocks [NBLK_W, NBLK_W+NBLK_X): cvt_x
// Both sides keep the proven vectorized bodies (8 elems/thread). Fusion
// saves one launch gap + one wave-ramp vs two dispatches; both streams are
// HBM-bound so bytes are unchanged.
#define NBLK_W ((KDIM * NDIM / 8) / 256)
#define NBLK_X ((MDIM * NDIM / 8) / 256)

__global__ __launch_bounds__(256) void prep_kernel(
    const int* __restrict__ Wq, const float* __restrict__ scales,
    const float* __restrict__ zeros, const int* __restrict__ mask,
    const float* __restrict__ scale2, const float* __restrict__ x,
    ushort_t* __restrict__ Wb, ushort_t* __restrict__ Xb) {
    const int b = blockIdx.x;
    if (b < NBLK_W) {
        int gid = b * 256 + threadIdx.x;
        int e0 = gid * 8;
        int k = e0 >> 12;
        int n = e0 & (NDIM - 1);
        int g = n >> 7;
        float ss = scales[k * NGRP + g] * scale2[k];
        float z  = zeros[k * NGRP + g];
        i32x4 q0 = *(const i32x4*)(Wq + e0);
        i32x4 q1 = *(const i32x4*)(Wq + e0 + 4);
        i32x4 m0 = *(const i32x4*)(mask + e0);
        i32x4 m1 = *(const i32x4*)(mask + e0 + 4);
        u16x8 r;
#pragma unroll
        for (int i = 0; i < 4; ++i) r[i]     = f2bf(((float)q0[i] - z) * ss * (float)m0[i]);
#pragma unroll
        for (int i = 0; i < 4; ++i) r[4 + i] = f2bf(((float)q1[i] - z) * ss * (float)m1[i]);
        *(u16x8*)(Wb + e0) = r;
    } else {
        int gid = (b - NBLK_W) * 256 + threadIdx.x;
        size_t e0 = (size_t)gid * 8;
        f32x4 a = *(const f32x4*)(x + e0);
        f32x4 c = *(const f32x4*)(x + e0 + 4);
        u16x8 r;
#pragma unroll
        for (int i = 0; i < 4; ++i) r[i] = f2bf(a[i]);
#pragma unroll
        for (int i = 0; i < 4; ++i) r[4 + i] = f2bf(c[i]);
        *(u16x8*)(Xb + e0) = r;
    }
}

// ---------------- Pass 2: 256x256-tile bf16 GEMM, read-pipelined --------
// Round-6 kernel EXACTLY (best measured: 218 us, 1261 TF, util 58.2%).
// out[m][k] = sum_n Xb[m][n] * Wb[k][n] + bias[k]
// 512 threads = 8 waves (2M x 4N). BK=64. LDS: 2 slots x {A0,A1,B0,B1}
// halves of [128][64] bf16 (16 KB each) = 128 KiB.
// Cluster order (0,0)->(0,1)->(1,1)->(1,0). EVERY ds_read overlaps a prior
// MFMA cluster (zero extra registers; B0/B1 reg roles alternate per tile):
//   B1[t]   read after (0,0) issues  (consumed by (0,1))
//   A1[t]   read after (0,1) issues  (a-regs WAR-free; consumed by (1,1))
//   B0[t+1] read after BAR3          (into dead B1-regs; consumed t+1 (0,0))
//   A0[t+1] read after (1,0) issues  (a-regs WAR-free; consumed t+1 (0,0))
// VMCNT6 after ST3 (before BAR3): forced set = oldest 8 = exactly tile
// t+1's halves (issued >=1 tile ago; landed free).
// Overwrite-safety chain and vmcnt ledger: see round-5/6 derivation.

#define LDS_SLOT 65536
#define LDS_A0   0
#define LDS_A1   16384
#define LDS_B0   32768
#define LDS_B1   49152

#define STAGE(ldsHalf, gbase) do { \
    gload_lds16((gbase) + goff0, (ldsHalf) + ldsoff0); \
    gload_lds16((gbase) + goff1, (ldsHalf) + ldsoff1); } while (0)

#define READ_A(S, QM) do { \
    const char* Ab_ = lds + (S)*LDS_SLOT + (QM)*16384 + rowA; \
    a00 = *(const bf16x8*)(Ab_ + 0*2048 + cb0); \
    a10 = *(const bf16x8*)(Ab_ + 1*2048 + cb0); \
    a20 = *(const bf16x8*)(Ab_ + 2*2048 + cb0); \
    a30 = *(const bf16x8*)(Ab_ + 3*2048 + cb0); \
    a01 = *(const bf16x8*)(Ab_ + 0*2048 + cb1); \
    a11 = *(const bf16x8*)(Ab_ + 1*2048 + cb1); \
    a21 = *(const bf16x8*)(Ab_ + 2*2048 + cb1); \
    a31 = *(const bf16x8*)(Ab_ + 3*2048 + cb1); \
} while (0)

#define READ_B(S, QN, B00, B10, B01, B11) do { \
    const char* Bb_ = lds + (S)*LDS_SLOT + 32768 + (QN)*16384 + rowB; \
    B00 = *(const bf16x8*)(Bb_ + 0*2048 + cb0); \
    B10 = *(const bf16x8*)(Bb_ + 1*2048 + cb0); \
    B01 = *(const bf16x8*)(Bb_ + 0*2048 + cb1); \
    B11 = *(const bf16x8*)(Bb_ + 1*2048 + cb1); \
} while (0)

#define MFMA16(QM, QN, B00, B10, B01, B11) do { \
    acc[(QM)*4+0][(QN)*2+0] = __builtin_amdgcn_mfma_f32_16x16x32_bf16(a00, B00, acc[(QM)*4+0][(QN)*2+0], 0,0,0); \
    acc[(QM)*4+1][(QN)*2+0] = __builtin_amdgcn_mfma_f32_16x16x32_bf16(a10, B00, acc[(QM)*4+1][(QN)*2+0], 0,0,0); \
    acc[(QM)*4+2][(QN)*2+0] = __builtin_amdgcn_mfma_f32_16x16x32_bf16(a20, B00, acc[(QM)*4+2][(QN)*2+0], 0,0,0); \
    acc[(QM)*4+3][(QN)*2+0] = __builtin_amdgcn_mfma_f32_16x16x32_bf16(a30, B00, acc[(QM)*4+3][(QN)*2+0], 0,0,0); \
    acc[(QM)*4+0][(QN)*2+1] = __builtin_amdgcn_mfma_f32_16x16x32_bf16(a00, B10, acc[(QM)*4+0][(QN)*2+1], 0,0,0); \
    acc[(QM)*4+1][(QN)*2+1] = __builtin_amdgcn_mfma_f32_16x16x32_bf16(a10, B10, acc[(QM)*4+1][(QN)*2+1], 0,0,0); \
    acc[(QM)*4+2][(QN)*2+1] = __builtin_amdgcn_mfma_f32_16x16x32_bf16(a20, B10, acc[(QM)*4+2][(QN)*2+1], 0,0,0); \
    acc[(QM)*4+3][(QN)*2+1] = __builtin_amdgcn_mfma_f32_16x16x32_bf16(a30, B10, acc[(QM)*4+3][(QN)*2+1], 0,0,0); \
    acc[(QM)*4+0][(QN)*2+0] = __builtin_amdgcn_mfma_f32_16x16x32_bf16(a01, B01, acc[(QM)*4+0][(QN)*2+0], 0,0,0); \
    acc[(QM)*4+1][(QN)*2+0] = __builtin_amdgcn_mfma_f32_16x16x32_bf16(a11, B01, acc[(QM)*4+1][(QN)*2+0], 0,0,0); \
    acc[(QM)*4+2][(QN)*2+0] = __builtin_amdgcn_mfma_f32_16x16x32_bf16(a21, B01, acc[(QM)*4+2][(QN)*2+0], 0,0,0); \
    acc[(QM)*4+3][(QN)*2+0] = __builtin_amdgcn_mfma_f32_16x16x32_bf16(a31, B01, acc[(QM)*4+3][(QN)*2+0], 0,0,0); \
    acc[(QM)*4+0][(QN)*2+1] = __builtin_amdgcn_mfma_f32_16x16x32_bf16(a01, B11, acc[(QM)*4+0][(QN)*2+1], 0,0,0); \
    acc[(QM)*4+1][(QN)*2+1] = __builtin_amdgcn_mfma_f32_16x16x32_bf16(a11, B11, acc[(QM)*4+1][(QN)*2+1], 0,0,0); \
    acc[(QM)*4+2][(QN)*2+1] = __builtin_amdgcn_mfma_f32_16x16x32_bf16(a21, B11, acc[(QM)*4+2][(QN)*2+1], 0,0,0); \
    acc[(QM)*4+3][(QN)*2+1] = __builtin_amdgcn_mfma_f32_16x16x32_bf16(a31, B11, acc[(QM)*4+3][(QN)*2+1], 0,0,0); \
} while (0)

#define BAR    asm volatile("s_barrier" ::: "memory")
#define VMCNT6 asm volatile("s_waitcnt vmcnt(6)" ::: "memory")
#define VMCNT0 asm volatile("s_waitcnt vmcnt(0)" ::: "memory")
#define SB     __builtin_amdgcn_sched_barrier(0)

#define CLUSTER(QM, QN, B00, B10, B01, B11) do { \
    SB; __builtin_amdgcn_s_setprio(1); \
    MFMA16(QM, QN, B00, B10, B01, B11); \
    __builtin_amdgcn_s_setprio(0); SB; \
} while (0)

// One K-tile. Entry state: a = A0[t], P = B0[t]. Exit: a = A0[t+1],
// Q = B0[t+1] (P/Q roles swap each tile).
#define TILE2(S, P00,P10,P01,P11, Q00,Q10,Q01,Q11, ST0, ST1, ST2, ST3, BND) do { \
    ST0; \
    CLUSTER(0, 0, P00,P10,P01,P11); \
    READ_B(S, 1, Q00,Q10,Q01,Q11); \
    BAR; \
    ST1; \
    CLUSTER(0, 1, Q00,Q10,Q01,Q11); \
    READ_A(S, 1); \
    BAR; \
    ST2; \
    CLUSTER(1, 1, Q00,Q10,Q01,Q11); \
    BAR; \
    ST3; \
    BND; \
    BAR; \
    READ_B((S)^1, 0, Q00,Q10,Q01,Q11); \
    CLUSTER(1, 0, P00,P10,P01,P11); \
    READ_A((S)^1, 0); \
} while (0)

__global__ __launch_bounds__(512, 2) void gemm8p_kernel(
    const ushort_t* __restrict__ Xb, const ushort_t* __restrict__ Wb,
    const float* __restrict__ bias, float* __restrict__ out) {
    extern __shared__ char lds[];

    const int tid   = threadIdx.x;
    const int lane  = tid & 63;
    const int wid   = tid >> 6;      // 0..7
    const int wm    = wid >> 2;      // 0..1  (M sub-block within each half)
    const int wn    = wid & 3;       // 0..3  (N sub-block within each half)
    const int fr    = lane & 15;
    const int khalf = lane >> 4;     // 0..3

    // T1: bijective XCD swizzle (512 % 8 == 0)
    const int orig  = blockIdx.x;
    const int wgid  = ((orig & 7) << 6) | (orig >> 3);
    const int ntile = wgid & 15;     // 16 N-tiles
    const int mtile = wgid >> 4;     // 32 M-tiles
    const int m0 = mtile << 8;
    const int n0 = ntile << 8;

    // stage addressing: granule g = l*512 + tid; LDS linear; global pre-swizzled
    const int g0 = tid, g1 = 512 + tid;
    const size_t goff0 = (size_t)(g0 >> 3) * NDIM + (size_t)((((g0 & 7) ^ ((g0 >> 3) & 7))) << 3);
    const size_t goff1 = (size_t)(g1 >> 3) * NDIM + (size_t)((((g1 & 7) ^ ((g1 >> 3) & 7))) << 3);
    const int ldsoff0 = (wid << 10);          // wave-uniform base, load 0
    const int ldsoff1 = 8192 + (wid << 10);   // load 1

    // fragment read offsets (bytes within a [128][64] bf16 half-buffer)
    const int rowA = ((wm << 6) + fr) << 7;               // (wm*64+fr)*128
    const int rowB = ((wn << 5) + fr) << 7;               // (wn*32+fr)*128
    const int cb0  = ((khalf)     ^ (fr & 7)) << 4;       // kk=0 chunk (swizzled)
    const int cb1  = ((4 + khalf) ^ (fr & 7)) << 4;       // kk=1 chunk

    f32x4 acc[8][4];
#pragma unroll
    for (int i = 0; i < 8; ++i)
#pragma unroll
        for (int j = 0; j < 4; ++j) { f32x4 z = {0.f,0.f,0.f,0.f}; acc[i][j] = z; }

    const ushort_t* Xrow0 = Xb + (size_t)m0 * NDIM;
    const ushort_t* Xrow1 = Xb + (size_t)(m0 + 128) * NDIM;
    const ushort_t* Wrow0 = Wb + (size_t)n0 * NDIM;
    const ushort_t* Wrow1 = Wb + (size_t)(n0 + 128) * NDIM;

    // fragment registers: a = current A-half; p/q = B0/B1 (roles alternate)
    bf16x8 a00, a10, a20, a30, a01, a11, a21, a31;
    bf16x8 p00, p10, p01, p11, q00, q10, q01, q11;

    // Prologue: tile 0 complete into slot 0 (8 loads), then B0[1],B1[1],A1[1]
    // into slot 1 (6 loads). vmcnt(6) forces tile 0 landed. Then read tile 0's
    // (0,0)-operands (one-time startup drain).
    STAGE(lds + 0*LDS_SLOT + LDS_A0, Xrow0 + 0);
    STAGE(lds + 0*LDS_SLOT + LDS_B0, Wrow0 + 0);
    STAGE(lds + 0*LDS_SLOT + LDS_B1, Wrow1 + 0);
    STAGE(lds + 0*LDS_SLOT + LDS_A1, Xrow1 + 0);
    STAGE(lds + 1*LDS_SLOT + LDS_B0, Wrow0 + 64);
    STAGE(lds + 1*LDS_SLOT + LDS_B1, Wrow1 + 64);
    STAGE(lds + 1*LDS_SLOT + LDS_A1, Xrow1 + 64);
    VMCNT6;
    BAR;
    READ_A(0, 0);
    READ_B(0, 0, p00, p10, p01, p11);

    // Hot loop: tiles 0..61 (all stage indices statically valid).
#pragma unroll 1
    for (int kt2 = 0; kt2 < NT / 2 - 1; ++kt2) {
        const int te = 2 * kt2, to = te + 1;
        TILE2(0, p00,p10,p01,p11, q00,q10,q01,q11,
              STAGE(lds + 1*LDS_SLOT + LDS_A0, Xrow0 + (te + 1) * 64),
              STAGE(lds + 0*LDS_SLOT + LDS_B0, Wrow0 + (te + 2) * 64),
              STAGE(lds + 0*LDS_SLOT + LDS_B1, Wrow1 + (te + 2) * 64),
              STAGE(lds + 0*LDS_SLOT + LDS_A1, Xrow1 + (te + 2) * 64),
              VMCNT6);
        TILE2(1, q00,q10,q01,q11, p00,p10,p01,p11,
              STAGE(lds + 0*LDS_SLOT + LDS_A0, Xrow0 + (to + 1) * 64),
              STAGE(lds + 1*LDS_SLOT + LDS_B0, Wrow0 + (to + 2) * 64),
              STAGE(lds + 1*LDS_SLOT + LDS_B1, Wrow1 + (to + 2) * 64),
              STAGE(lds + 1*LDS_SLOT + LDS_A1, Xrow1 + (to + 2) * 64),
              VMCNT6);
    }
    // Peeled tile 62 (slot 0): only A0[63] stage; vmcnt(0) at its boundary
    // (tail: steady forcing breaks). Its pre-reads fetch tile 63's operands.
    TILE2(0, p00,p10,p01,p11, q00,q10,q01,q11,
          STAGE(lds + 1*LDS_SLOT + LDS_A0, Xrow0 + 63 * 64),
          (void)0, (void)0, (void)0,
          VMCNT0);
    // Peeled tile 63 (slot 1): no stages; trailing pre-reads are dead (DCE).
    TILE2(1, q00,q10,q01,q11, p00,p10,p01,p11,
          (void)0, (void)0, (void)0, (void)0, (void)0);

    // Epilogue: C/D layout col=lane&15, row=(lane>>4)*4+reg.
    // row(i) = m0 + (i>>2)*128 + wm*64 + (i&3)*16 + khalf*4 + q
    // col(j) = n0 + (j>>1)*128 + wn*32 + (j&1)*16 + fr
    float bv[4];
#pragma unroll
    for (int j = 0; j < 4; ++j)
        bv[j] = bias[n0 + ((j >> 1) << 7) + (wn << 5) + ((j & 1) << 4) + fr];
#pragma unroll
    for (int i = 0; i < 8; ++i) {
        const int row = m0 + ((i >> 2) << 7) + (wm << 6) + ((i & 3) << 4) + (khalf << 2);
#pragma unroll
        for (int j = 0; j < 4; ++j) {
            const int col = n0 + ((j >> 1) << 7) + (wn << 5) + ((j & 1) << 4) + fr;
#pragma unroll
            for (int q = 0; q < 4; ++q)
                out[(size_t)(row + q) * KDIM + col] = acc[i][j][q] + bv[j];
        }
    }
}

// ---------------- Fallback (only if ws too small): naive fused ----------------
__global__ __launch_bounds__(256) void naive_kernel(
    const float* __restrict__ x, const int* __restrict__ Wq,
    const float* __restrict__ scales, const float* __restrict__ zeros,
    const int* __restrict__ mask, const float* __restrict__ scale2,
    const float* __restrict__ bias, float* __restrict__ out) {
    size_t o = (size_t)blockIdx.x * 256 + threadIdx.x;
    int m = (int)(o >> 12);
    int k = (int)(o & (KDIM - 1));
    const float* xr = x + (size_t)m * NDIM;
    const int* wr = Wq + (size_t)k * NDIM;
    const int* mr = mask + (size_t)k * NDIM;
    float s2 = scale2[k];
    float acc = 0.f;
    for (int g = 0; g < NGRP; ++g) {
        float ss = scales[k * NGRP + g] * s2;
        float z = zeros[k * NGRP + g];
        for (int n = g * GSZ; n < (g + 1) * GSZ; ++n)
            acc += xr[n] * (((float)wr[n] - z) * ss * (float)mr[n]);
    }
    out[o] = acc + bias[k];
}

extern "C" void kernel_launch(void* const* d_in, const int* in_sizes, int n_in,
                              void* d_out, int out_size, void* d_ws, size_t ws_size,
                              hipStream_t stream) {
    const float* x      = (const float*)d_in[0];
    const int*   Wq     = (const int*)d_in[1];
    const float* scales = (const float*)d_in[2];
    const float* zeros  = (const float*)d_in[3];
    const int*   mask   = (const int*)d_in[4];
    const float* scale2 = (const float*)d_in[5];
    const float* bias   = (const float*)d_in[6];
    float* out = (float*)d_out;

    const size_t needW = (size_t)KDIM * NDIM * sizeof(ushort_t);  // 32 MiB
    const size_t needX = (size_t)MDIM * NDIM * sizeof(ushort_t);  // 64 MiB

    if (ws_size >= needW + needX) {
        ushort_t* Wb = (ushort_t*)d_ws;
        ushort_t* Xb = (ushort_t*)((char*)d_ws + needW);
        hipLaunchKernelGGL(prep_kernel, dim3(NBLK_W + NBLK_X), dim3(256),
                           0, stream, Wq, scales, zeros, mask, scale2, x, Wb, Xb);
        hipFuncSetAttribute((const void*)gemm8p_kernel,
                            hipFuncAttributeMaxDynamicSharedMemorySize, 131072);
        hipLaunchKernelGGL(gemm8p_kernel, dim3((MDIM / 256) * (KDIM / 256)), dim3(512),
                           131072, stream, Xb, Wb, bias, out);
    } else {
        hipLaunchKernelGGL(naive_kernel, dim3((MDIM * KDIM) / 256), dim3(256),
                           0, stream, x, Wq, scales, zeros, mask, scale2, bias, out);
    }
}

// Round 12
// 181.927 us; speedup vs baseline: 1.6493x; 1.4879x over previous
//
#include <hip/hip_runtime.h>
#include <hip/hip_bf16.h>
#include <cstdint>
#include <cstddef>

#define KDIM 4096   // out features
#define NDIM 4096   // in features (contraction dim)
#define NGRP 32
#define GSZ  128
#define MDIM 8192   // 4 * 2048 rows of x
#define NT   (NDIM / 64)   // 64 K-tiles of BK=64

typedef float f32x4 __attribute__((ext_vector_type(4)));
typedef int   v4i  __attribute__((ext_vector_type(4)));

__device__ __forceinline__ void gload_lds16(const void* g, void* l) {
    __builtin_amdgcn_global_load_lds(
        (const __attribute__((address_space(1))) unsigned int*)g,
        (__attribute__((address_space(3))) unsigned int*)l,
        16, 0, 0);
}

// ------- Pass 1: per-row absmax quantize to i8 ---------------------------
// blocks [0, KDIM): W rows  (dequant -> rowmax -> i8 + sw[k])
// blocks [KDIM, KDIM+MDIM): x rows (rowmax -> i8 + sx[m])
// Row-constant scale => i32 accumulation is exact across the whole K loop;
// single f32 rescale in the GEMM epilogue.
__global__ __launch_bounds__(256) void prep8_kernel(
    const int* __restrict__ Wq, const float* __restrict__ scales,
    const float* __restrict__ zeros, const int* __restrict__ mask,
    const float* __restrict__ scale2, const float* __restrict__ x,
    signed char* __restrict__ W8, signed char* __restrict__ X8,
    float* __restrict__ sw, float* __restrict__ sx) {
    __shared__ float sm[4];
    const int tid = threadIdx.x;
    const int b = blockIdx.x;
    float v[16];
    if (b < KDIM) {
        const int e0 = tid * 16;                 // 16 contiguous elems, one group
        const int g  = tid >> 3;                 // (tid*16)>>7
        const float ss = scales[b * NGRP + g] * scale2[b];
        const float z  = zeros[b * NGRP + g];
        const int* qp = Wq   + (size_t)b * NDIM + e0;
        const int* mp = mask + (size_t)b * NDIM + e0;
#pragma unroll
        for (int c = 0; c < 4; ++c) {
            v4i q = *(const v4i*)(qp + c * 4);
            v4i m = *(const v4i*)(mp + c * 4);
#pragma unroll
            for (int k = 0; k < 4; ++k)
                v[c * 4 + k] = ((float)q[k] - z) * ss * (float)m[k];
        }
    } else {
        const float* xp = x + (size_t)(b - KDIM) * NDIM + tid * 16;
#pragma unroll
        for (int c = 0; c < 4; ++c) {
            f32x4 a = *(const f32x4*)(xp + c * 4);
#pragma unroll
            for (int k = 0; k < 4; ++k) v[c * 4 + k] = a[k];
        }
    }
    float vmax = 0.f;
#pragma unroll
    for (int i = 0; i < 16; ++i) vmax = fmaxf(vmax, fabsf(v[i]));
#pragma unroll
    for (int off = 32; off >= 1; off >>= 1)
        vmax = fmaxf(vmax, __shfl_xor(vmax, off));
    if ((tid & 63) == 0) sm[tid >> 6] = vmax;
    __syncthreads();
    vmax = fmaxf(fmaxf(sm[0], sm[1]), fmaxf(sm[2], sm[3]));
    const float inv = vmax > 0.f ? 127.f / vmax : 0.f;
    v4i pk;
#pragma unroll
    for (int c = 0; c < 4; ++c) {
        int b0 = __float2int_rn(v[c * 4 + 0] * inv) & 255;
        int b1 = __float2int_rn(v[c * 4 + 1] * inv) & 255;
        int b2 = __float2int_rn(v[c * 4 + 2] * inv) & 255;
        int b3 = __float2int_rn(v[c * 4 + 3] * inv);
        pk[c] = b0 | (b1 << 8) | (b2 << 16) | (b3 << 24);
    }
    if (b < KDIM) {
        *(v4i*)(W8 + (size_t)b * NDIM + tid * 16) = pk;
        if (tid == 0) sw[b] = vmax * (1.f / 127.f);
    } else {
        *(v4i*)(X8 + (size_t)(b - KDIM) * NDIM + tid * 16) = pk;
        if (tid == 0) sx[b - KDIM] = vmax * (1.f / 127.f);
    }
}

// ---------------- Pass 2: 256x256-tile i8 GEMM, r6-proven schedule -------
// out[m][k] = (sum_n X8[m][n]*W8[k][n]) * sx[m]*sw[k] + bias[k]
// mfma_i32_16x16x64_i8 (2x bf16 rate): 4 clusters x 8 MFMAs per BK=64 tile.
// LDS: 2 slots x {A0,A1,B0,B1} halves of [128][64] i8 (8 KB) = 64 KiB.
// Fragment layout (same pattern as verified bf16 16x16x32): lane l = row
// (l&15), 16 contiguous k at (l>>4)*16 -> chunk = khalf; XOR swizzle
// chunk ^= (row&3) on both stage-source and ds_read (involution).
// Schedule/barriers/read-pipelining: byte-identical r6 topology.
// vmcnt ledger (1 gload/thread/STAGE): steady entry 3 outstanding
// ({B0,B1,A1}[t+1]); ST0..ST3 -> 7; BND vmcnt(3) forces oldest 4 = exactly
// tile t+1's halves. Prologue 7 loads + vmcnt(3). Tile 62: vmcnt(0).

#define LDS_SLOT 32768
#define LDS_A0   0
#define LDS_A1   8192
#define LDS_B0   16384
#define LDS_B1   24576

#define STAGE(ldsHalf, gbase) gload_lds16((gbase) + goff, (ldsHalf) + ldsoff)

#define READ_A(S, QM) do { \
    const char* Ab_ = lds + (S)*LDS_SLOT + (QM)*8192 + rowA; \
    a0 = *(const v4i*)(Ab_ + 0*1024 + cb); \
    a1 = *(const v4i*)(Ab_ + 1*1024 + cb); \
    a2 = *(const v4i*)(Ab_ + 2*1024 + cb); \
    a3 = *(const v4i*)(Ab_ + 3*1024 + cb); \
} while (0)

#define READ_B(S, QN, B0, B1) do { \
    const char* Bb_ = lds + (S)*LDS_SLOT + 16384 + (QN)*8192 + rowB; \
    B0 = *(const v4i*)(Bb_ + 0*1024 + cb); \
    B1 = *(const v4i*)(Bb_ + 1*1024 + cb); \
} while (0)

#define BAR    asm volatile("s_barrier" ::: "memory")
#define VMCNT3 asm volatile("s_waitcnt vmcnt(3)" ::: "memory")
#define VMCNT0 asm volatile("s_waitcnt vmcnt(0)" ::: "memory")
#define SB     __builtin_amdgcn_sched_barrier(0)

#define CLUSTER8(QM, QN, B0, B1) do { \
    SB; __builtin_amdgcn_s_setprio(1); \
    acc[(QM)*4+0][(QN)*2+0] = __builtin_amdgcn_mfma_i32_16x16x64_i8(a0, B0, acc[(QM)*4+0][(QN)*2+0], 0,0,0); \
    acc[(QM)*4+0][(QN)*2+1] = __builtin_amdgcn_mfma_i32_16x16x64_i8(a0, B1, acc[(QM)*4+0][(QN)*2+1], 0,0,0); \
    acc[(QM)*4+1][(QN)*2+0] = __builtin_amdgcn_mfma_i32_16x16x64_i8(a1, B0, acc[(QM)*4+1][(QN)*2+0], 0,0,0); \
    acc[(QM)*4+1][(QN)*2+1] = __builtin_amdgcn_mfma_i32_16x16x64_i8(a1, B1, acc[(QM)*4+1][(QN)*2+1], 0,0,0); \
    acc[(QM)*4+2][(QN)*2+0] = __builtin_amdgcn_mfma_i32_16x16x64_i8(a2, B0, acc[(QM)*4+2][(QN)*2+0], 0,0,0); \
    acc[(QM)*4+2][(QN)*2+1] = __builtin_amdgcn_mfma_i32_16x16x64_i8(a2, B1, acc[(QM)*4+2][(QN)*2+1], 0,0,0); \
    acc[(QM)*4+3][(QN)*2+0] = __builtin_amdgcn_mfma_i32_16x16x64_i8(a3, B0, acc[(QM)*4+3][(QN)*2+0], 0,0,0); \
    acc[(QM)*4+3][(QN)*2+1] = __builtin_amdgcn_mfma_i32_16x16x64_i8(a3, B1, acc[(QM)*4+3][(QN)*2+1], 0,0,0); \
    __builtin_amdgcn_s_setprio(0); SB; \
} while (0)

// One K-tile (r6 topology). Entry: a = A0[t], P = B0[t]. Exit: a = A0[t+1],
// Q = B0[t+1] (P/Q roles swap each tile).
#define TILE2(S, P0,P1, Q0,Q1, ST0, ST1, ST2, ST3, BND) do { \
    ST0; \
    CLUSTER8(0, 0, P0, P1); \
    READ_B(S, 1, Q0, Q1); \
    BAR; \
    ST1; \
    CLUSTER8(0, 1, Q0, Q1); \
    READ_A(S, 1); \
    BAR; \
    ST2; \
    CLUSTER8(1, 1, Q0, Q1); \
    BAR; \
    ST3; \
    BND; \
    BAR; \
    READ_B((S)^1, 0, Q0, Q1); \
    CLUSTER8(1, 0, P0, P1); \
    READ_A((S)^1, 0); \
} while (0)

__global__ __launch_bounds__(512, 2) void gemm8p_kernel(
    const signed char* __restrict__ X8, const signed char* __restrict__ W8,
    const float* __restrict__ sx, const float* __restrict__ sw,
    const float* __restrict__ bias, float* __restrict__ out) {
    extern __shared__ char lds[];

    const int tid   = threadIdx.x;
    const int lane  = tid & 63;
    const int wid   = tid >> 6;      // 0..7
    const int wm    = wid >> 2;      // 0..1  (M sub-block within each half)
    const int wn    = wid & 3;       // 0..3  (N sub-block within each half)
    const int fr    = lane & 15;
    const int khalf = lane >> 4;     // 0..3

    // T1: bijective XCD swizzle (512 % 8 == 0)
    const int orig  = blockIdx.x;
    const int wgid  = ((orig & 7) << 6) | (orig >> 3);
    const int ntile = wgid & 15;     // 16 N-tiles
    const int mtile = wgid >> 4;     // 32 M-tiles
    const int m0 = mtile << 8;
    const int n0 = ntile << 8;

    // stage addressing: granule = tid (16B); LDS linear; global pre-swizzled
    const size_t goff = (size_t)(tid >> 2) * NDIM
                      + (size_t)(((tid & 3) ^ ((tid >> 2) & 3)) << 4);
    const int ldsoff = (wid << 10);   // wave-uniform base + lane*16 implicit

    // fragment read offsets (bytes within a [128][64] i8 half-buffer)
    const int rowA = ((wm << 6) + fr) << 6;          // (wm*64+fr)*64
    const int rowB = ((wn << 5) + fr) << 6;          // (wn*32+fr)*64
    const int cb   = (khalf ^ (fr & 3)) << 4;        // swizzled k-chunk

    v4i acc[8][4];
#pragma unroll
    for (int i = 0; i < 8; ++i)
#pragma unroll
        for (int j = 0; j < 4; ++j) { v4i z = {0, 0, 0, 0}; acc[i][j] = z; }

    const signed char* Xrow0 = X8 + (size_t)m0 * NDIM;
    const signed char* Xrow1 = X8 + (size_t)(m0 + 128) * NDIM;
    const signed char* Wrow0 = W8 + (size_t)n0 * NDIM;
    const signed char* Wrow1 = W8 + (size_t)(n0 + 128) * NDIM;

    // fragment registers: a = current A-half (4 frags); p/q = B pairs
    v4i a0, a1, a2, a3;
    v4i p0, p1, q0, q1;

    // Prologue: tile 0's four halves into slot 0, then B0/B1/A1[1] into
    // slot 1 (7 loads). vmcnt(3) forces tile 0 landed, leaves 3 = steady
    // entry state. A0[1] staged at tile 0's ST0 (steady rule).
    STAGE(lds + 0*LDS_SLOT + LDS_A0, Xrow0 + 0);
    STAGE(lds + 0*LDS_SLOT + LDS_B0, Wrow0 + 0);
    STAGE(lds + 0*LDS_SLOT + LDS_B1, Wrow1 + 0);
    STAGE(lds + 0*LDS_SLOT + LDS_A1, Xrow1 + 0);
    STAGE(lds + 1*LDS_SLOT + LDS_B0, Wrow0 + 64);
    STAGE(lds + 1*LDS_SLOT + LDS_B1, Wrow1 + 64);
    STAGE(lds + 1*LDS_SLOT + LDS_A1, Xrow1 + 64);
    VMCNT3;
    BAR;
    READ_A(0, 0);
    READ_B(0, 0, p0, p1);

    // Hot loop: tiles 0..61.
#pragma unroll 1
    for (int kt2 = 0; kt2 < NT / 2 - 1; ++kt2) {
        const int te = 2 * kt2, to = te + 1;
        TILE2(0, p0,p1, q0,q1,
              STAGE(lds + 1*LDS_SLOT + LDS_A0, Xrow0 + (te + 1) * 64),
              STAGE(lds + 0*LDS_SLOT + LDS_B0, Wrow0 + (te + 2) * 64),
              STAGE(lds + 0*LDS_SLOT + LDS_B1, Wrow1 + (te + 2) * 64),
              STAGE(lds + 0*LDS_SLOT + LDS_A1, Xrow1 + (te + 2) * 64),
              VMCNT3);
        TILE2(1, q0,q1, p0,p1,
              STAGE(lds + 0*LDS_SLOT + LDS_A0, Xrow0 + (to + 1) * 64),
              STAGE(lds + 1*LDS_SLOT + LDS_B0, Wrow0 + (to + 2) * 64),
              STAGE(lds + 1*LDS_SLOT + LDS_B1, Wrow1 + (to + 2) * 64),
              STAGE(lds + 1*LDS_SLOT + LDS_A1, Xrow1 + (to + 2) * 64),
              VMCNT3);
    }
    // Peeled tile 62 (slot 0): only A0[63]; vmcnt(0) at its boundary (4
    // outstanding: {B0,B1,A1}[63] + A0[63]).
    TILE2(0, p0,p1, q0,q1,
          STAGE(lds + 1*LDS_SLOT + LDS_A0, Xrow0 + 63 * 64),
          (void)0, (void)0, (void)0,
          VMCNT0);
    // Peeled tile 63 (slot 1): no stages; trailing pre-reads are dead.
    TILE2(1, q0,q1, p0,p1,
          (void)0, (void)0, (void)0, (void)0, (void)0);

    // Epilogue: C/D layout (dtype-independent): col=lane&15, row=(lane>>4)*4+reg.
    // row(i) = m0 + (i>>2)*128 + wm*64 + (i&3)*16 + khalf*4 + q
    // col(j) = n0 + (j>>1)*128 + wn*32 + (j&1)*16 + fr
    float bv[4], swv[4];
#pragma unroll
    for (int j = 0; j < 4; ++j) {
        const int col = n0 + ((j >> 1) << 7) + (wn << 5) + ((j & 1) << 4) + fr;
        bv[j]  = bias[col];
        swv[j] = sw[col];
    }
#pragma unroll
    for (int i = 0; i < 8; ++i) {
        const int row = m0 + ((i >> 2) << 7) + (wm << 6) + ((i & 3) << 4) + (khalf << 2);
        float sxq[4];
#pragma unroll
        for (int q = 0; q < 4; ++q) sxq[q] = sx[row + q];
#pragma unroll
        for (int j = 0; j < 4; ++j) {
            const int col = n0 + ((j >> 1) << 7) + (wn << 5) + ((j & 1) << 4) + fr;
#pragma unroll
            for (int q = 0; q < 4; ++q)
                out[(size_t)(row + q) * KDIM + col] =
                    (float)acc[i][j][q] * (sxq[q] * swv[j]) + bv[j];
        }
    }
}

// ---------------- Fallback (only if ws too small): naive fused ----------------
__global__ __launch_bounds__(256) void naive_kernel(
    const float* __restrict__ x, const int* __restrict__ Wq,
    const float* __restrict__ scales, const float* __restrict__ zeros,
    const int* __restrict__ mask, const float* __restrict__ scale2,
    const float* __restrict__ bias, float* __restrict__ out) {
    size_t o = (size_t)blockIdx.x * 256 + threadIdx.x;
    int m = (int)(o >> 12);
    int k = (int)(o & (KDIM - 1));
    const float* xr = x + (size_t)m * NDIM;
    const int* wr = Wq + (size_t)k * NDIM;
    const int* mr = mask + (size_t)k * NDIM;
    float s2 = scale2[k];
    float acc = 0.f;
    for (int g = 0; g < NGRP; ++g) {
        float ss = scales[k * NGRP + g] * s2;
        float z = zeros[k * NGRP + g];
        for (int n = g * GSZ; n < (g + 1) * GSZ; ++n)
            acc += xr[n] * (((float)wr[n] - z) * ss * (float)mr[n]);
    }
    out[o] = acc + bias[k];
}

extern "C" void kernel_launch(void* const* d_in, const int* in_sizes, int n_in,
                              void* d_out, int out_size, void* d_ws, size_t ws_size,
                              hipStream_t stream) {
    const float* x      = (const float*)d_in[0];
    const int*   Wq     = (const int*)d_in[1];
    const float* scales = (const float*)d_in[2];
    const float* zeros  = (const float*)d_in[3];
    const int*   mask   = (const int*)d_in[4];
    const float* scale2 = (const float*)d_in[5];
    const float* bias   = (const float*)d_in[6];
    float* out = (float*)d_out;

    const size_t offW  = 0;
    const size_t offX  = (size_t)KDIM * NDIM;                   // 16 MiB
    const size_t offSW = offX + (size_t)MDIM * NDIM;            // +32 MiB
    const size_t offSX = offSW + KDIM * sizeof(float);
    const size_t need  = offSX + MDIM * sizeof(float);

    if (ws_size >= need) {
        signed char* W8 = (signed char*)d_ws + offW;
        signed char* X8 = (signed char*)d_ws + offX;
        float* sw = (float*)((char*)d_ws + offSW);
        float* sx = (float*)((char*)d_ws + offSX);
        hipLaunchKernelGGL(prep8_kernel, dim3(KDIM + MDIM), dim3(256),
                           0, stream, Wq, scales, zeros, mask, scale2, x,
                           W8, X8, sw, sx);
        hipFuncSetAttribute((const void*)gemm8p_kernel,
                            hipFuncAttributeMaxDynamicSharedMemorySize, 65536);
        hipLaunchKernelGGL(gemm8p_kernel, dim3((MDIM / 256) * (KDIM / 256)), dim3(512),
                           65536, stream, X8, W8, sx, sw, bias, out);
    } else {
        hipLaunchKernelGGL(naive_kernel, dim3((MDIM * KDIM) / 256), dim3(256),
                           0, stream, x, Wq, scales, zeros, mask, scale2, bias, out);
    }
}

// Round 13
// 181.205 us; speedup vs baseline: 1.6558x; 1.0040x over previous
//
#include <hip/hip_runtime.h>
#include <hip/hip_bf16.h>
#include <cstdint>
#include <cstddef>

#define KDIM 4096   // out features
#define NDIM 4096   // in features (contraction dim)
#define NGRP 32
#define GSZ  128
#define MDIM 8192   // 4 * 2048 rows of x
#define NT   (NDIM / 64)   // 64 K-tiles of BK=64

typedef float f32x4 __attribute__((ext_vector_type(4)));
typedef int   v4i  __attribute__((ext_vector_type(4)));

__device__ __forceinline__ void gload_lds16(const void* g, void* l) {
    __builtin_amdgcn_global_load_lds(
        (const __attribute__((address_space(1))) unsigned int*)g,
        (__attribute__((address_space(3))) unsigned int*)l,
        16, 0, 0);
}

// ------- Pass 1: per-row absmax quantize to i8 ---------------------------
// blocks [0, KDIM): W rows  (dequant -> rowmax -> i8 + sw[k])
// blocks [KDIM, KDIM+MDIM): x rows (rowmax -> i8 + sx[m])
// Row-constant scale => i32 accumulation is exact across the whole K loop;
// single f32 rescale in the GEMM epilogue.
__global__ __launch_bounds__(256) void prep8_kernel(
    const int* __restrict__ Wq, const float* __restrict__ scales,
    const float* __restrict__ zeros, const int* __restrict__ mask,
    const float* __restrict__ scale2, const float* __restrict__ x,
    signed char* __restrict__ W8, signed char* __restrict__ X8,
    float* __restrict__ sw, float* __restrict__ sx) {
    __shared__ float sm[4];
    const int tid = threadIdx.x;
    const int b = blockIdx.x;
    float v[16];
    if (b < KDIM) {
        const int e0 = tid * 16;                 // 16 contiguous elems, one group
        const int g  = tid >> 3;                 // (tid*16)>>7
        const float ss = scales[b * NGRP + g] * scale2[b];
        const float z  = zeros[b * NGRP + g];
        const int* qp = Wq   + (size_t)b * NDIM + e0;
        const int* mp = mask + (size_t)b * NDIM + e0;
#pragma unroll
        for (int c = 0; c < 4; ++c) {
            v4i q = *(const v4i*)(qp + c * 4);
            v4i m = *(const v4i*)(mp + c * 4);
#pragma unroll
            for (int k = 0; k < 4; ++k)
                v[c * 4 + k] = ((float)q[k] - z) * ss * (float)m[k];
        }
    } else {
        const float* xp = x + (size_t)(b - KDIM) * NDIM + tid * 16;
#pragma unroll
        for (int c = 0; c < 4; ++c) {
            f32x4 a = *(const f32x4*)(xp + c * 4);
#pragma unroll
            for (int k = 0; k < 4; ++k) v[c * 4 + k] = a[k];
        }
    }
    float vmax = 0.f;
#pragma unroll
    for (int i = 0; i < 16; ++i) vmax = fmaxf(vmax, fabsf(v[i]));
#pragma unroll
    for (int off = 32; off >= 1; off >>= 1)
        vmax = fmaxf(vmax, __shfl_xor(vmax, off));
    if ((tid & 63) == 0) sm[tid >> 6] = vmax;
    __syncthreads();
    vmax = fmaxf(fmaxf(sm[0], sm[1]), fmaxf(sm[2], sm[3]));
    const float inv = vmax > 0.f ? 127.f / vmax : 0.f;
    v4i pk;
#pragma unroll
    for (int c = 0; c < 4; ++c) {
        int b0 = __float2int_rn(v[c * 4 + 0] * inv) & 255;
        int b1 = __float2int_rn(v[c * 4 + 1] * inv) & 255;
        int b2 = __float2int_rn(v[c * 4 + 2] * inv) & 255;
        int b3 = __float2int_rn(v[c * 4 + 3] * inv);
        pk[c] = b0 | (b1 << 8) | (b2 << 16) | (b3 << 24);
    }
    if (b < KDIM) {
        *(v4i*)(W8 + (size_t)b * NDIM + tid * 16) = pk;
        if (tid == 0) sw[b] = vmax * (1.f / 127.f);
    } else {
        *(v4i*)(X8 + (size_t)(b - KDIM) * NDIM + tid * 16) = pk;
        if (tid == 0) sx[b - KDIM] = vmax * (1.f / 127.f);
    }
}

// ---------------- Pass 2: 256x256-tile i8 GEMM, r6-proven schedule -------
// out[m][k] = (sum_n X8[m][n]*W8[k][n]) * sx[m]*sw[k] + bias[k]
// mfma_i32_16x16x64_i8 (2x bf16 rate): 4 clusters x 8 MFMAs per BK=64 tile.
// LDS: 2 slots x {A0,A1,B0,B1} halves of [128][64] i8 (8 KB) = 64 KiB.
// Fragment layout: lane l = row (l&15), 16 contiguous k at (l>>4)*16.
// SWIZZLE (round-13 fix): i8 rows are 64B (4 chunks, HALF the banks; bank
// slot = 4*(row&1) + chunk). Old g(row)=row&3 left consecutive-16-lane
// groups on only 4 of 8 slots (4-way conflict, 1.26e7 measured). New
// g(row) = (row>>1)&3: slots over 8 consecutive lanes = {kh^j, 4+(kh^j)}
// j=0..3 = all 8 slots, <=2 lanes each (2-way = free, m136). Involution:
// stage-source chunk (t&3)^((t>>3)&3) [row=t>>2], read chunk
// khalf^((fr>>1)&3); subtile rows differ by 16 -> same g -> consistent.
// Schedule/barriers/read-pipelining: byte-identical r6 topology.
// vmcnt ledger (1 gload/thread/STAGE): steady entry 3 outstanding
// ({B0,B1,A1}[t+1]); ST0..ST3 -> 7; BND vmcnt(3) forces oldest 4 = exactly
// tile t+1's halves. Prologue 7 loads + vmcnt(3). Tile 62: vmcnt(0).

#define LDS_SLOT 32768
#define LDS_A0   0
#define LDS_A1   8192
#define LDS_B0   16384
#define LDS_B1   24576

#define STAGE(ldsHalf, gbase) gload_lds16((gbase) + goff, (ldsHalf) + ldsoff)

#define READ_A(S, QM) do { \
    const char* Ab_ = lds + (S)*LDS_SLOT + (QM)*8192 + rowA; \
    a0 = *(const v4i*)(Ab_ + 0*1024 + cb); \
    a1 = *(const v4i*)(Ab_ + 1*1024 + cb); \
    a2 = *(const v4i*)(Ab_ + 2*1024 + cb); \
    a3 = *(const v4i*)(Ab_ + 3*1024 + cb); \
} while (0)

#define READ_B(S, QN, B0, B1) do { \
    const char* Bb_ = lds + (S)*LDS_SLOT + 16384 + (QN)*8192 + rowB; \
    B0 = *(const v4i*)(Bb_ + 0*1024 + cb); \
    B1 = *(const v4i*)(Bb_ + 1*1024 + cb); \
} while (0)

#define BAR    asm volatile("s_barrier" ::: "memory")
#define VMCNT3 asm volatile("s_waitcnt vmcnt(3)" ::: "memory")
#define VMCNT0 asm volatile("s_waitcnt vmcnt(0)" ::: "memory")
#define SB     __builtin_amdgcn_sched_barrier(0)

#define CLUSTER8(QM, QN, B0, B1) do { \
    SB; __builtin_amdgcn_s_setprio(1); \
    acc[(QM)*4+0][(QN)*2+0] = __builtin_amdgcn_mfma_i32_16x16x64_i8(a0, B0, acc[(QM)*4+0][(QN)*2+0], 0,0,0); \
    acc[(QM)*4+0][(QN)*2+1] = __builtin_amdgcn_mfma_i32_16x16x64_i8(a0, B1, acc[(QM)*4+0][(QN)*2+1], 0,0,0); \
    acc[(QM)*4+1][(QN)*2+0] = __builtin_amdgcn_mfma_i32_16x16x64_i8(a1, B0, acc[(QM)*4+1][(QN)*2+0], 0,0,0); \
    acc[(QM)*4+1][(QN)*2+1] = __builtin_amdgcn_mfma_i32_16x16x64_i8(a1, B1, acc[(QM)*4+1][(QN)*2+1], 0,0,0); \
    acc[(QM)*4+2][(QN)*2+0] = __builtin_amdgcn_mfma_i32_16x16x64_i8(a2, B0, acc[(QM)*4+2][(QN)*2+0], 0,0,0); \
    acc[(QM)*4+2][(QN)*2+1] = __builtin_amdgcn_mfma_i32_16x16x64_i8(a2, B1, acc[(QM)*4+2][(QN)*2+1], 0,0,0); \
    acc[(QM)*4+3][(QN)*2+0] = __builtin_amdgcn_mfma_i32_16x16x64_i8(a3, B0, acc[(QM)*4+3][(QN)*2+0], 0,0,0); \
    acc[(QM)*4+3][(QN)*2+1] = __builtin_amdgcn_mfma_i32_16x16x64_i8(a3, B1, acc[(QM)*4+3][(QN)*2+1], 0,0,0); \
    __builtin_amdgcn_s_setprio(0); SB; \
} while (0)

// One K-tile (r6 topology). Entry: a = A0[t], P = B0[t]. Exit: a = A0[t+1],
// Q = B0[t+1] (P/Q roles swap each tile).
#define TILE2(S, P0,P1, Q0,Q1, ST0, ST1, ST2, ST3, BND) do { \
    ST0; \
    CLUSTER8(0, 0, P0, P1); \
    READ_B(S, 1, Q0, Q1); \
    BAR; \
    ST1; \
    CLUSTER8(0, 1, Q0, Q1); \
    READ_A(S, 1); \
    BAR; \
    ST2; \
    CLUSTER8(1, 1, Q0, Q1); \
    BAR; \
    ST3; \
    BND; \
    BAR; \
    READ_B((S)^1, 0, Q0, Q1); \
    CLUSTER8(1, 0, P0, P1); \
    READ_A((S)^1, 0); \
} while (0)

__global__ __launch_bounds__(512, 2) void gemm8p_kernel(
    const signed char* __restrict__ X8, const signed char* __restrict__ W8,
    const float* __restrict__ sx, const float* __restrict__ sw,
    const float* __restrict__ bias, float* __restrict__ out) {
    extern __shared__ char lds[];

    const int tid   = threadIdx.x;
    const int lane  = tid & 63;
    const int wid   = tid >> 6;      // 0..7
    const int wm    = wid >> 2;      // 0..1  (M sub-block within each half)
    const int wn    = wid & 3;       // 0..3  (N sub-block within each half)
    const int fr    = lane & 15;
    const int khalf = lane >> 4;     // 0..3

    // T1: bijective XCD swizzle (512 % 8 == 0)
    const int orig  = blockIdx.x;
    const int wgid  = ((orig & 7) << 6) | (orig >> 3);
    const int ntile = wgid & 15;     // 16 N-tiles
    const int mtile = wgid >> 4;     // 32 M-tiles
    const int m0 = mtile << 8;
    const int n0 = ntile << 8;

    // stage addressing: granule = tid (16B); LDS linear; global pre-swizzled
    // with g(row)=(row>>1)&3, row = tid>>2 -> XOR (tid>>3)&3.
    const size_t goff = (size_t)(tid >> 2) * NDIM
                      + (size_t)(((tid & 3) ^ ((tid >> 3) & 3)) << 4);
    const int ldsoff = (wid << 10);   // wave-uniform base + lane*16 implicit

    // fragment read offsets (bytes within a [128][64] i8 half-buffer)
    const int rowA = ((wm << 6) + fr) << 6;          // (wm*64+fr)*64
    const int rowB = ((wn << 5) + fr) << 6;          // (wn*32+fr)*64
    const int cb   = (khalf ^ ((fr >> 1) & 3)) << 4; // swizzled k-chunk

    v4i acc[8][4];
#pragma unroll
    for (int i = 0; i < 8; ++i)
#pragma unroll
        for (int j = 0; j < 4; ++j) { v4i z = {0, 0, 0, 0}; acc[i][j] = z; }

    const signed char* Xrow0 = X8 + (size_t)m0 * NDIM;
    const signed char* Xrow1 = X8 + (size_t)(m0 + 128) * NDIM;
    const signed char* Wrow0 = W8 + (size_t)n0 * NDIM;
    const signed char* Wrow1 = W8 + (size_t)(n0 + 128) * NDIM;

    // fragment registers: a = current A-half (4 frags); p/q = B pairs
    v4i a0, a1, a2, a3;
    v4i p0, p1, q0, q1;

    // Prologue: tile 0's four halves into slot 0, then B0/B1/A1[1] into
    // slot 1 (7 loads). vmcnt(3) forces tile 0 landed, leaves 3 = steady
    // entry state. A0[1] staged at tile 0's ST0 (steady rule).
    STAGE(lds + 0*LDS_SLOT + LDS_A0, Xrow0 + 0);
    STAGE(lds + 0*LDS_SLOT + LDS_B0, Wrow0 + 0);
    STAGE(lds + 0*LDS_SLOT + LDS_B1, Wrow1 + 0);
    STAGE(lds + 0*LDS_SLOT + LDS_A1, Xrow1 + 0);
    STAGE(lds + 1*LDS_SLOT + LDS_B0, Wrow0 + 64);
    STAGE(lds + 1*LDS_SLOT + LDS_B1, Wrow1 + 64);
    STAGE(lds + 1*LDS_SLOT + LDS_A1, Xrow1 + 64);
    VMCNT3;
    BAR;
    READ_A(0, 0);
    READ_B(0, 0, p0, p1);

    // Hot loop: tiles 0..61.
#pragma unroll 1
    for (int kt2 = 0; kt2 < NT / 2 - 1; ++kt2) {
        const int te = 2 * kt2, to = te + 1;
        TILE2(0, p0,p1, q0,q1,
              STAGE(lds + 1*LDS_SLOT + LDS_A0, Xrow0 + (te + 1) * 64),
              STAGE(lds + 0*LDS_SLOT + LDS_B0, Wrow0 + (te + 2) * 64),
              STAGE(lds + 0*LDS_SLOT + LDS_B1, Wrow1 + (te + 2) * 64),
              STAGE(lds + 0*LDS_SLOT + LDS_A1, Xrow1 + (te + 2) * 64),
              VMCNT3);
        TILE2(1, q0,q1, p0,p1,
              STAGE(lds + 0*LDS_SLOT + LDS_A0, Xrow0 + (to + 1) * 64),
              STAGE(lds + 1*LDS_SLOT + LDS_B0, Wrow0 + (to + 2) * 64),
              STAGE(lds + 1*LDS_SLOT + LDS_B1, Wrow1 + (to + 2) * 64),
              STAGE(lds + 1*LDS_SLOT + LDS_A1, Xrow1 + (to + 2) * 64),
              VMCNT3);
    }
    // Peeled tile 62 (slot 0): only A0[63]; vmcnt(0) at its boundary (4
    // outstanding: {B0,B1,A1}[63] + A0[63]).
    TILE2(0, p0,p1, q0,q1,
          STAGE(lds + 1*LDS_SLOT + LDS_A0, Xrow0 + 63 * 64),
          (void)0, (void)0, (void)0,
          VMCNT0);
    // Peeled tile 63 (slot 1): no stages; trailing pre-reads are dead.
    TILE2(1, q0,q1, p0,p1,
          (void)0, (void)0, (void)0, (void)0, (void)0);

    // Epilogue: C/D layout (dtype-independent): col=lane&15, row=(lane>>4)*4+reg.
    // row(i) = m0 + (i>>2)*128 + wm*64 + (i&3)*16 + khalf*4 + q
    // col(j) = n0 + (j>>1)*128 + wn*32 + (j&1)*16 + fr
    float bv[4], swv[4];
#pragma unroll
    for (int j = 0; j < 4; ++j) {
        const int col = n0 + ((j >> 1) << 7) + (wn << 5) + ((j & 1) << 4) + fr;
        bv[j]  = bias[col];
        swv[j] = sw[col];
    }
#pragma unroll
    for (int i = 0; i < 8; ++i) {
        const int row = m0 + ((i >> 2) << 7) + (wm << 6) + ((i & 3) << 4) + (khalf << 2);
        float sxq[4];
#pragma unroll
        for (int q = 0; q < 4; ++q) sxq[q] = sx[row + q];
#pragma unroll
        for (int j = 0; j < 4; ++j) {
            const int col = n0 + ((j >> 1) << 7) + (wn << 5) + ((j & 1) << 4) + fr;
#pragma unroll
            for (int q = 0; q < 4; ++q)
                out[(size_t)(row + q) * KDIM + col] =
                    (float)acc[i][j][q] * (sxq[q] * swv[j]) + bv[j];
        }
    }
}

// ---------------- Fallback (only if ws too small): naive fused ----------------
__global__ __launch_bounds__(256) void naive_kernel(
    const float* __restrict__ x, const int* __restrict__ Wq,
    const float* __restrict__ scales, const float* __restrict__ zeros,
    const int* __restrict__ mask, const float* __restrict__ scale2,
    const float* __restrict__ bias, float* __restrict__ out) {
    size_t o = (size_t)blockIdx.x * 256 + threadIdx.x;
    int m = (int)(o >> 12);
    int k = (int)(o & (KDIM - 1));
    const float* xr = x + (size_t)m * NDIM;
    const int* wr = Wq + (size_t)k * NDIM;
    const int* mr = mask + (size_t)k * NDIM;
    float s2 = scale2[k];
    float acc = 0.f;
    for (int g = 0; g < NGRP; ++g) {
        float ss = scales[k * NGRP + g] * s2;
        float z = zeros[k * NGRP + g];
        for (int n = g * GSZ; n < (g + 1) * GSZ; ++n)
            acc += xr[n] * (((float)wr[n] - z) * ss * (float)mr[n]);
    }
    out[o] = acc + bias[k];
}

extern "C" void kernel_launch(void* const* d_in, const int* in_sizes, int n_in,
                              void* d_out, int out_size, void* d_ws, size_t ws_size,
                              hipStream_t stream) {
    const float* x      = (const float*)d_in[0];
    const int*   Wq     = (const int*)d_in[1];
    const float* scales = (const float*)d_in[2];
    const float* zeros  = (const float*)d_in[3];
    const int*   mask   = (const int*)d_in[4];
    const float* scale2 = (const float*)d_in[5];
    const float* bias   = (const float*)d_in[6];
    float* out = (float*)d_out;

    const size_t offW  = 0;
    const size_t offX  = (size_t)KDIM * NDIM;                   // 16 MiB
    const size_t offSW = offX + (size_t)MDIM * NDIM;            // +32 MiB
    const size_t offSX = offSW + KDIM * sizeof(float);
    const size_t need  = offSX + MDIM * sizeof(float);

    if (ws_size >= need) {
        signed char* W8 = (signed char*)d_ws + offW;
        signed char* X8 = (signed char*)d_ws + offX;
        float* sw = (float*)((char*)d_ws + offSW);
        float* sx = (float*)((char*)d_ws + offSX);
        hipLaunchKernelGGL(prep8_kernel, dim3(KDIM + MDIM), dim3(256),
                           0, stream, Wq, scales, zeros, mask, scale2, x,
                           W8, X8, sw, sx);
        hipFuncSetAttribute((const void*)gemm8p_kernel,
                            hipFuncAttributeMaxDynamicSharedMemorySize, 65536);
        hipLaunchKernelGGL(gemm8p_kernel, dim3((MDIM / 256) * (KDIM / 256)), dim3(512),
                           65536, stream, X8, W8, sx, sw, bias, out);
    } else {
        hipLaunchKernelGGL(naive_kernel, dim3((MDIM * KDIM) / 256), dim3(256),
                           0, stream, x, Wq, scales, zeros, mask, scale2, bias, out);
    }
}